// Round 1
// baseline (972.146 us; speedup 1.0000x reference)
//
#include <hip/hip_runtime.h>
#include <math.h>

#define NB 8
#define TT 2048
#define DD 1024

typedef __attribute__((ext_vector_type(8))) short short8;
typedef __attribute__((ext_vector_type(4))) float floatx4;

__device__ inline unsigned short f2bf(float f) {
    unsigned u = __builtin_bit_cast(unsigned, f);
    unsigned r = (u + 0x7fffu + ((u >> 16) & 1u)) >> 16;
    return (unsigned short)r;
}

// ---------------- kernel 0: normalize ema (1 block, 256 threads) -------------
__global__ void k_ema(const float* __restrict__ ema, float* __restrict__ ema_n) {
    __shared__ float red[4];
    __shared__ float sinv;
    int tid = threadIdx.x;
    float4 v = reinterpret_cast<const float4*>(ema)[tid];
    float ss = v.x * v.x + v.y * v.y + v.z * v.z + v.w * v.w;
    for (int off = 32; off; off >>= 1) ss += __shfl_down(ss, off);
    if ((tid & 63) == 0) red[tid >> 6] = ss;
    __syncthreads();
    if (tid == 0) {
        float s = red[0] + red[1] + red[2] + red[3];
        sinv = 1.0f / fmaxf(sqrtf(s), 1e-12f);
    }
    __syncthreads();
    float inv = sinv;
    float4 o;
    o.x = v.x * inv; o.y = v.y * inv; o.z = v.z * inv; o.w = v.w * inv;
    reinterpret_cast<float4*>(ema_n)[tid] = o;
}

// ------------- kernel A: gelu + row norm + ema dot (1 block per row) ---------
__global__ void k_gelu_norm(const float* __restrict__ x, const float* __restrict__ ema_n,
                            float* __restrict__ out, unsigned short* __restrict__ onrm,
                            float* __restrict__ ema_sim) {
    __shared__ float redss[4], reddt[4];
    __shared__ float sinv, sdot;
    int row = blockIdx.x;             // b*T + t
    int tid = threadIdx.x;            // 256 threads, 4 elems each
    const float c = 0.7978845608028654f;
    float4 v = reinterpret_cast<const float4*>(x + (size_t)row * DD)[tid];
    float4 e = reinterpret_cast<const float4*>(ema_n)[tid];
    float vv[4] = {v.x, v.y, v.z, v.w};
    float ee[4] = {e.x, e.y, e.z, e.w};
    float g[4];
    float ss = 0.f, dt = 0.f;
#pragma unroll
    for (int i = 0; i < 4; i++) {
        float xx = vv[i];
        float th = tanhf(c * (xx + 0.044715f * xx * xx * xx));
        float o = 0.5f * xx * (1.0f + th);
        g[i] = o;
        ss += o * o;
        dt += o * ee[i];
    }
    for (int off = 32; off; off >>= 1) {
        ss += __shfl_down(ss, off);
        dt += __shfl_down(dt, off);
    }
    if ((tid & 63) == 0) { redss[tid >> 6] = ss; reddt[tid >> 6] = dt; }
    __syncthreads();
    if (tid == 0) {
        float s = redss[0] + redss[1] + redss[2] + redss[3];
        float d = reddt[0] + reddt[1] + reddt[2] + reddt[3];
        sinv = 1.0f / fmaxf(sqrtf(s), 1e-12f);
        sdot = d;
    }
    __syncthreads();
    float inv = sinv;
    float4 o;
    o.x = g[0]; o.y = g[1]; o.z = g[2]; o.w = g[3];
    reinterpret_cast<float4*>(out + (size_t)row * DD)[tid] = o;
    ushort4 u;
    u.x = f2bf(g[0] * inv);
    u.y = f2bf(g[1] * inv);
    u.z = f2bf(g[2] * inv);
    u.w = f2bf(g[3] * inv);
    reinterpret_cast<ushort4*>(onrm + (size_t)row * DD)[tid] = u;
    if (tid == 0) ema_sim[row] = sdot * inv;
}

// -------- kernel B: causal max similarity via bf16 MFMA 16x16x32 -------------
// grid: NB * (TT/64) blocks, 256 threads (4 waves). Wave w owns t rows
// [ti*64 + w*16, +16). Loops s-tiles of 16 up to and including the diagonal.
__global__ void k_seqmax(const unsigned short* __restrict__ onrm,
                         float* __restrict__ seqmax) {
    int bi = blockIdx.x >> 5;     // /32 t-tiles
    int ti = blockIdx.x & 31;
    int wave = threadIdx.x >> 6;
    int lane = threadIdx.x & 63;
    int t0 = ti * 64 + wave * 16;
    const unsigned short* base = onrm + (size_t)bi * TT * DD;
    int arow = t0 + (lane & 15);
    int kblk = (lane >> 4) * 8;
    const short8* aptr = reinterpret_cast<const short8*>(base + (size_t)arow * DD + kblk);
    float rmax[4] = {-2.f, -2.f, -2.f, -2.f};
    for (int s0 = 0; s0 <= t0; s0 += 16) {
        const short8* bptr =
            reinterpret_cast<const short8*>(base + (size_t)(s0 + (lane & 15)) * DD + kblk);
        floatx4 acc0 = {0.f, 0.f, 0.f, 0.f};
        floatx4 acc1 = {0.f, 0.f, 0.f, 0.f};
#pragma unroll 4
        for (int k0 = 0; k0 < DD; k0 += 64) {
            short8 a0 = aptr[k0 >> 3];
            short8 a1 = aptr[(k0 >> 3) + 4];
            short8 b0 = bptr[k0 >> 3];
            short8 b1 = bptr[(k0 >> 3) + 4];
            acc0 = __builtin_amdgcn_mfma_f32_16x16x32_bf16(a0, b0, acc0, 0, 0, 0);
            acc1 = __builtin_amdgcn_mfma_f32_16x16x32_bf16(a1, b1, acc1, 0, 0, 0);
        }
        int trow_base = t0 + ((lane >> 4) << 2);
        int scol = s0 + (lane & 15);
#pragma unroll
        for (int r = 0; r < 4; r++) {
            float vsum = acc0[r] + acc1[r];
            rmax[r] = fmaxf(rmax[r], (scol < trow_base + r) ? vsum : -2.0f);
        }
    }
    // reduce max across the 16 lanes holding the same rows (low 4 lane bits)
#pragma unroll
    for (int m = 1; m < 16; m <<= 1) {
#pragma unroll
        for (int r = 0; r < 4; r++) rmax[r] = fmaxf(rmax[r], __shfl_xor(rmax[r], m));
    }
    if ((lane & 15) == 0) {
        int trow_base = t0 + ((lane >> 4) << 2);
#pragma unroll
        for (int r = 0; r < 4; r++) seqmax[bi * TT + trow_base + r] = rmax[r];
    }
}

// ---------------- kernel C: gate + scale (1 block per row) -------------------
__global__ void k_gate(float* __restrict__ out, const float* __restrict__ ema_sim,
                       const float* __restrict__ seqmax,
                       const float* __restrict__ log_tau,
                       const float* __restrict__ log_blend,
                       const float* __restrict__ logit_blend_seq) {
    int row = blockIdx.x;
    int t = row & (TT - 1);
    int tid = threadIdx.x;
    float tau = expf(log_tau[0]);
    float alpha = 1.f / (1.f + expf(-log_blend[0]));
    float wseq = 1.f / (1.f + expf(-logit_blend_seq[0]));
    float es = ema_sim[row];
    float sq = (t > 0) ? seqmax[row] : es;
    float fam = wseq * sq + (1.f - wseq) * es;
    float gate = 1.f - alpha + alpha * expf(-tau * fam);
    float4 v = reinterpret_cast<float4*>(out + (size_t)row * DD)[tid];
    v.x *= gate; v.y *= gate; v.z *= gate; v.w *= gate;
    reinterpret_cast<float4*>(out + (size_t)row * DD)[tid] = v;
}

extern "C" void kernel_launch(void* const* d_in, const int* in_sizes, int n_in,
                              void* d_out, int out_size, void* d_ws, size_t ws_size,
                              hipStream_t stream) {
    const float* x = (const float*)d_in[0];
    const float* ema = (const float*)d_in[1];
    // d_in[2] = logit_decay (unused by reference)
    const float* log_tau = (const float*)d_in[3];
    const float* log_blend = (const float*)d_in[4];
    const float* logit_bs = (const float*)d_in[5];
    float* out = (float*)d_out;

    char* ws = (char*)d_ws;
    float* ema_n = (float*)ws;                         // 4 KB
    float* ema_sim = (float*)(ws + (4 << 10));         // 64 KB
    float* seqmax = (float*)(ws + (68 << 10));         // 64 KB
    unsigned short* onrm = (unsigned short*)(ws + (1 << 20));  // 32 MB bf16 out_norm

    k_ema<<<1, 256, 0, stream>>>(ema, ema_n);
    k_gelu_norm<<<NB * TT, 256, 0, stream>>>(x, ema_n, out, onrm, ema_sim);
    k_seqmax<<<NB * (TT / 64), 256, 0, stream>>>(onrm, seqmax);
    k_gate<<<NB * TT, 256, 0, stream>>>(out, ema_sim, seqmax, log_tau, log_blend, logit_bs);
}

// Round 2
// 130.695 us; speedup vs baseline: 7.4383x; 7.4383x over previous
//
#include <hip/hip_runtime.h>
#include <math.h>

#define NB 8
#define TT 2048
#define DD 1024

typedef __attribute__((ext_vector_type(8))) short short8;
typedef __attribute__((ext_vector_type(4))) float floatx4;

__device__ inline unsigned short f2bf(float f) {
    unsigned u = __builtin_bit_cast(unsigned, f);
    unsigned r = (u + 0x7fffu + ((u >> 16) & 1u)) >> 16;
    return (unsigned short)r;
}

// ---------------- kernel 0: normalize ema (1 block, 256 threads) -------------
__global__ void k_ema(const float* __restrict__ ema, float* __restrict__ ema_n) {
    __shared__ float red[4];
    __shared__ float sinv;
    int tid = threadIdx.x;
    float4 v = reinterpret_cast<const float4*>(ema)[tid];
    float ss = v.x * v.x + v.y * v.y + v.z * v.z + v.w * v.w;
    for (int off = 32; off; off >>= 1) ss += __shfl_down(ss, off);
    if ((tid & 63) == 0) red[tid >> 6] = ss;
    __syncthreads();
    if (tid == 0) {
        float s = red[0] + red[1] + red[2] + red[3];
        sinv = 1.0f / fmaxf(sqrtf(s), 1e-12f);
    }
    __syncthreads();
    float inv = sinv;
    float4 o;
    o.x = v.x * inv; o.y = v.y * inv; o.z = v.z * inv; o.w = v.w * inv;
    reinterpret_cast<float4*>(ema_n)[tid] = o;
}

// ------------- kernel A: gelu + row norm + ema dot (1 block per row) ---------
__global__ void k_gelu_norm(const float* __restrict__ x, const float* __restrict__ ema_n,
                            float* __restrict__ out, unsigned short* __restrict__ onrm,
                            float* __restrict__ ema_sim) {
    __shared__ float redss[4], reddt[4];
    __shared__ float sinv, sdot;
    int row = blockIdx.x;             // b*T + t
    int tid = threadIdx.x;            // 256 threads, 4 elems each
    const float c = 0.7978845608028654f;
    float4 v = reinterpret_cast<const float4*>(x + (size_t)row * DD)[tid];
    float4 e = reinterpret_cast<const float4*>(ema_n)[tid];
    float vv[4] = {v.x, v.y, v.z, v.w};
    float ee[4] = {e.x, e.y, e.z, e.w};
    float g[4];
    float ss = 0.f, dt = 0.f;
#pragma unroll
    for (int i = 0; i < 4; i++) {
        float xx = vv[i];
        float th = tanhf(c * (xx + 0.044715f * xx * xx * xx));
        float o = 0.5f * xx * (1.0f + th);
        g[i] = o;
        ss += o * o;
        dt += o * ee[i];
    }
    for (int off = 32; off; off >>= 1) {
        ss += __shfl_down(ss, off);
        dt += __shfl_down(dt, off);
    }
    if ((tid & 63) == 0) { redss[tid >> 6] = ss; reddt[tid >> 6] = dt; }
    __syncthreads();
    if (tid == 0) {
        float s = redss[0] + redss[1] + redss[2] + redss[3];
        float d = reddt[0] + reddt[1] + reddt[2] + reddt[3];
        sinv = 1.0f / fmaxf(sqrtf(s), 1e-12f);
        sdot = d;
    }
    __syncthreads();
    float inv = sinv;
    float4 o;
    o.x = g[0]; o.y = g[1]; o.z = g[2]; o.w = g[3];
    reinterpret_cast<float4*>(out + (size_t)row * DD)[tid] = o;
    ushort4 u;
    u.x = f2bf(g[0] * inv);
    u.y = f2bf(g[1] * inv);
    u.z = f2bf(g[2] * inv);
    u.w = f2bf(g[3] * inv);
    reinterpret_cast<ushort4*>(onrm + (size_t)row * DD)[tid] = u;
    if (tid == 0) ema_sim[row] = sdot * inv;
}

// -------- kernel B: causal max similarity, tiled bf16 MFMA GEMM --------------
// grid = NB * 528 (lower-triangular 64x64 tile pairs). 256 thr = 4 waves,
// each wave owns a 32x32 quadrant (2x2 MFMA frags). BK=64, double-buffered
// LDS staged via global_load_lds w=16 with XOR-swizzled global source.
__global__ void k_seqmax(const unsigned short* __restrict__ onrm,
                         float* __restrict__ part) {
    __shared__ unsigned short lds[2][2][4096];   // [buf][A/B][64 rows x 64 bf16]

    int b = blockIdx.x / 528;
    int p = blockIdx.x % 528;
    int ti = (int)((sqrtf(8.0f * (float)p + 1.0f) - 1.0f) * 0.5f);
    while ((ti + 1) * (ti + 2) / 2 <= p) ++ti;
    while (ti * (ti + 1) / 2 > p) --ti;
    int sj = p - ti * (ti + 1) / 2;

    int lane = threadIdx.x & 63;
    int wave = threadIdx.x >> 6;
    int wr = wave >> 1, wc = wave & 1;

    const unsigned short* Abase = onrm + (size_t)(b * TT + ti * 64) * DD;
    const unsigned short* Bbase = onrm + (size_t)(b * TT + sj * 64) * DD;

    floatx4 acc[2][2];
#pragma unroll
    for (int i = 0; i < 2; i++)
#pragma unroll
        for (int j = 0; j < 2; j++) acc[i][j] = (floatx4){0.f, 0.f, 0.f, 0.f};

    // stage one 64x64 bf16 tile pair (A,B) into lds[buf] for K-step kt.
    // LDS dest is linear (chunk_base + lane*16); global src column is
    // XOR-pre-swizzled so swizzled ds_reads see the right data.
    auto stage = [&](int buf, int kt) {
#pragma unroll
        for (int i = 0; i < 2; ++i) {
            int c = wave * 2 + i;            // chunk 0..7, 1KB each
            int off = c * 1024 + lane * 16;  // linear LDS byte offset
            int row = off >> 7;              // 128 B per row
            int colb = (off & 127) ^ ((row & 7) << 4);
            const char* srcA = (const char*)(Abase + (size_t)row * DD + kt * 64) + colb;
            const char* srcB = (const char*)(Bbase + (size_t)row * DD + kt * 64) + colb;
            __builtin_amdgcn_global_load_lds(
                (const __attribute__((address_space(1))) unsigned int*)srcA,
                (__attribute__((address_space(3))) unsigned int*)((char*)&lds[buf][0][0] + c * 1024),
                16, 0, 0);
            __builtin_amdgcn_global_load_lds(
                (const __attribute__((address_space(1))) unsigned int*)srcB,
                (__attribute__((address_space(3))) unsigned int*)((char*)&lds[buf][1][0] + c * 1024),
                16, 0, 0);
        }
    };

    stage(0, 0);
    __syncthreads();

    for (int kt = 0; kt < 16; ++kt) {
        int buf = kt & 1;
        if (kt + 1 < 16) stage(buf ^ 1, kt + 1);
        const char* Ab = (const char*)&lds[buf][0][0];
        const char* Bb = (const char*)&lds[buf][1][0];
#pragma unroll
        for (int ks = 0; ks < 2; ++ks) {
            short8 af[2], bg[2];
#pragma unroll
            for (int f = 0; f < 2; ++f) {
                int ar = wr * 32 + f * 16 + (lane & 15);
                int br = wc * 32 + f * 16 + (lane & 15);
                int cb = ks * 64 + ((lane >> 4) << 4);
                af[f] = *(const short8*)(Ab + ar * 128 + (cb ^ ((ar & 7) << 4)));
                bg[f] = *(const short8*)(Bb + br * 128 + (cb ^ ((br & 7) << 4)));
            }
#pragma unroll
            for (int fi = 0; fi < 2; ++fi)
#pragma unroll
                for (int fj = 0; fj < 2; ++fj)
                    acc[fi][fj] = __builtin_amdgcn_mfma_f32_16x16x32_bf16(
                        af[fi], bg[fj], acc[fi][fj], 0, 0, 0);
        }
        __syncthreads();
    }

    // epilogue: strict-causal mask, row-max over this block's 32-col half,
    // write partial to part[b][sj*2+wc][t]
    int g = lane >> 4;
    int t0g = ti * 64;
    int s0g = sj * 64;
#pragma unroll
    for (int fi = 0; fi < 2; ++fi) {
#pragma unroll
        for (int r = 0; r < 4; ++r) {
            int trow = t0g + wr * 32 + fi * 16 + g * 4 + r;
            float m = -2.0f;
#pragma unroll
            for (int fj = 0; fj < 2; ++fj) {
                int scol = s0g + wc * 32 + fj * 16 + (lane & 15);
                float v = (scol < trow) ? acc[fi][fj][r] : -2.0f;
                m = fmaxf(m, v);
            }
#pragma unroll
            for (int msk = 1; msk < 16; msk <<= 1) m = fmaxf(m, __shfl_xor(m, msk));
            if ((lane & 15) == 0) {
                part[((size_t)(b * 64 + sj * 2 + wc) << 11) + trow - 0 * t0g] = m;
            }
        }
    }
}

// -------- kernel B2: reduce partial maxes over sj halves ---------------------
__global__ void k_reduce(const float* __restrict__ part, float* __restrict__ seqmax) {
    int idx = blockIdx.x * 256 + threadIdx.x;   // 0 .. NB*TT
    int b = idx >> 11;
    int t = idx & (TT - 1);
    int ti = t >> 6;
    int n = (ti + 1) * 2;
    float m = -2.0f;
    for (int j = 0; j < n; ++j) m = fmaxf(m, part[((size_t)(b * 64 + j) << 11) + t]);
    seqmax[idx] = m;
}

// ---------------- kernel C: gate + scale (1 block per row) -------------------
__global__ void k_gate(float* __restrict__ out, const float* __restrict__ ema_sim,
                       const float* __restrict__ seqmax,
                       const float* __restrict__ log_tau,
                       const float* __restrict__ log_blend,
                       const float* __restrict__ logit_blend_seq) {
    int row = blockIdx.x;
    int t = row & (TT - 1);
    int tid = threadIdx.x;
    float tau = expf(log_tau[0]);
    float alpha = 1.f / (1.f + expf(-log_blend[0]));
    float wseq = 1.f / (1.f + expf(-logit_blend_seq[0]));
    float es = ema_sim[row];
    float sq = (t > 0) ? seqmax[row] : es;
    float fam = wseq * sq + (1.f - wseq) * es;
    float gate = 1.f - alpha + alpha * expf(-tau * fam);
    float4 v = reinterpret_cast<float4*>(out + (size_t)row * DD)[tid];
    v.x *= gate; v.y *= gate; v.z *= gate; v.w *= gate;
    reinterpret_cast<float4*>(out + (size_t)row * DD)[tid] = v;
}

extern "C" void kernel_launch(void* const* d_in, const int* in_sizes, int n_in,
                              void* d_out, int out_size, void* d_ws, size_t ws_size,
                              hipStream_t stream) {
    const float* x = (const float*)d_in[0];
    const float* ema = (const float*)d_in[1];
    // d_in[2] = logit_decay (unused by reference)
    const float* log_tau = (const float*)d_in[3];
    const float* log_blend = (const float*)d_in[4];
    const float* logit_bs = (const float*)d_in[5];
    float* out = (float*)d_out;

    char* ws = (char*)d_ws;
    float* ema_n = (float*)ws;                           // 4 KB
    float* ema_sim = (float*)(ws + (4 << 10));           // 64 KB
    float* seqmax = (float*)(ws + (68 << 10));           // 64 KB
    float* part = (float*)(ws + (132 << 10));            // 4 MB (8*64*2048 f32)
    unsigned short* onrm = (unsigned short*)(ws + ((size_t)4300 << 10));  // 32 MB

    k_ema<<<1, 256, 0, stream>>>(ema, ema_n);
    k_gelu_norm<<<NB * TT, 256, 0, stream>>>(x, ema_n, out, onrm, ema_sim);
    k_seqmax<<<NB * 528, 256, 0, stream>>>(onrm, part);
    k_reduce<<<NB * TT / 256, 256, 0, stream>>>(part, seqmax);
    k_gate<<<NB * TT, 256, 0, stream>>>(out, ema_sim, seqmax, log_tau, log_blend, logit_bs);
}

// Round 3
// 101.332 us; speedup vs baseline: 9.5936x; 1.2898x over previous
//
#include <hip/hip_runtime.h>
#include <math.h>

#define NB 8
#define TT 2048
#define DD 1024
#define NTI 16            // 2048 / 128 t-tiles
#define NPAIR 136         // NTI*(NTI+1)/2

typedef __attribute__((ext_vector_type(8))) short short8;
typedef __attribute__((ext_vector_type(4))) float floatx4;

__device__ inline unsigned short f2bf(float f) {
    unsigned u = __builtin_bit_cast(unsigned, f);
    unsigned r = (u + 0x7fffu + ((u >> 16) & 1u)) >> 16;
    return (unsigned short)r;
}

__device__ inline float fast_gelu(float x) {
    // tanh(z) = 1 - 2/(exp(2z)+1); __expf -> v_exp_f32
    float z = 0.7978845608028654f * (x + 0.044715f * x * x * x);
    float e = __expf(2.0f * z);
    float th = 1.0f - 2.0f / (e + 1.0f);
    return 0.5f * x * (1.0f + th);
}

// ---------------- kernel 0: normalize ema (1 block, 256 threads) -------------
__global__ void k_ema(const float* __restrict__ ema, float* __restrict__ ema_n) {
    __shared__ float red[4];
    __shared__ float sinv;
    int tid = threadIdx.x;
    float4 v = reinterpret_cast<const float4*>(ema)[tid];
    float ss = v.x * v.x + v.y * v.y + v.z * v.z + v.w * v.w;
    for (int off = 32; off; off >>= 1) ss += __shfl_down(ss, off);
    if ((tid & 63) == 0) red[tid >> 6] = ss;
    __syncthreads();
    if (tid == 0) {
        float s = red[0] + red[1] + red[2] + red[3];
        sinv = 1.0f / fmaxf(sqrtf(s), 1e-12f);
    }
    __syncthreads();
    float inv = sinv;
    float4 o;
    o.x = v.x * inv; o.y = v.y * inv; o.z = v.z * inv; o.w = v.w * inv;
    reinterpret_cast<float4*>(ema_n)[tid] = o;
}

// ------- kernel A: gelu + row norm + ema dot -> bf16 out_norm, ema_sim -------
__global__ void k_gelu_norm(const float* __restrict__ x, const float* __restrict__ ema_n,
                            unsigned short* __restrict__ onrm,
                            float* __restrict__ ema_sim) {
    __shared__ float redss[4], reddt[4];
    __shared__ float sinv, sdot;
    int row = blockIdx.x;             // b*T + t
    int tid = threadIdx.x;            // 256 threads, 4 elems each
    float4 v = reinterpret_cast<const float4*>(x + (size_t)row * DD)[tid];
    float4 e = reinterpret_cast<const float4*>(ema_n)[tid];
    float vv[4] = {v.x, v.y, v.z, v.w};
    float ee[4] = {e.x, e.y, e.z, e.w};
    float g[4];
    float ss = 0.f, dt = 0.f;
#pragma unroll
    for (int i = 0; i < 4; i++) {
        float o = fast_gelu(vv[i]);
        g[i] = o;
        ss += o * o;
        dt += o * ee[i];
    }
    for (int off = 32; off; off >>= 1) {
        ss += __shfl_down(ss, off);
        dt += __shfl_down(dt, off);
    }
    if ((tid & 63) == 0) { redss[tid >> 6] = ss; reddt[tid >> 6] = dt; }
    __syncthreads();
    if (tid == 0) {
        float s = redss[0] + redss[1] + redss[2] + redss[3];
        float d = reddt[0] + reddt[1] + reddt[2] + reddt[3];
        sinv = 1.0f / fmaxf(sqrtf(s), 1e-12f);
        sdot = d;
    }
    __syncthreads();
    float inv = sinv;
    ushort4 u;
    u.x = f2bf(g[0] * inv);
    u.y = f2bf(g[1] * inv);
    u.z = f2bf(g[2] * inv);
    u.w = f2bf(g[3] * inv);
    reinterpret_cast<ushort4*>(onrm + (size_t)row * DD)[tid] = u;
    if (tid == 0) ema_sim[row] = sdot * inv;
}

// -------- kernel B: causal max similarity, 128x128 tiled bf16 MFMA GEMM ------
// grid = NB*136 lower-tri 128x128 tile pairs, XCD-swizzled so each XCD owns
// one batch (4 MB onrm slice fits its 4 MB L2). 4 waves, each 64x64 (4x4
// frags), BK=64, double-buffered 64 KB LDS via global_load_lds w=16 with
// XOR-pre-swizzled global source (linear LDS dest).
__global__ void k_seqmax(const unsigned short* __restrict__ onrm,
                         float* __restrict__ part) {
    __shared__ unsigned short lds[2][2][8192];   // [buf][A/B][128 rows x 64 bf16]

    int id = blockIdx.x;
    int nid = (id & 7) * NPAIR + (id >> 3);      // bijective: 1088 % 8 == 0
    int b = nid / NPAIR;
    int p = nid % NPAIR;
    int ti = (int)((sqrtf(8.0f * (float)p + 1.0f) - 1.0f) * 0.5f);
    while ((ti + 1) * (ti + 2) / 2 <= p) ++ti;
    while (ti * (ti + 1) / 2 > p) --ti;
    int sj = p - ti * (ti + 1) / 2;

    int lane = threadIdx.x & 63;
    int wave = threadIdx.x >> 6;
    int wr = wave >> 1, wc = wave & 1;

    const unsigned short* Abase = onrm + (size_t)(b * TT + ti * 128) * DD;
    const unsigned short* Bbase = onrm + (size_t)(b * TT + sj * 128) * DD;

    floatx4 acc[4][4];
#pragma unroll
    for (int i = 0; i < 4; i++)
#pragma unroll
        for (int j = 0; j < 4; j++) acc[i][j] = (floatx4){0.f, 0.f, 0.f, 0.f};

    // stage 128x64 bf16 tiles (16 KB each): 16 chunks of 1 KB, 4 per wave.
    auto stage = [&](int buf, int kt) {
#pragma unroll
        for (int i = 0; i < 4; ++i) {
            int c = wave * 4 + i;            // chunk 0..15
            int off = c * 1024 + lane * 16;  // linear LDS byte offset
            int row = off >> 7;              // 128 B per row
            int colb = (off & 127) ^ ((row & 7) << 4);
            const char* srcA = (const char*)(Abase + (size_t)row * DD + kt * 64) + colb;
            const char* srcB = (const char*)(Bbase + (size_t)row * DD + kt * 64) + colb;
            __builtin_amdgcn_global_load_lds(
                (const __attribute__((address_space(1))) unsigned int*)srcA,
                (__attribute__((address_space(3))) unsigned int*)((char*)&lds[buf][0][0] + c * 1024),
                16, 0, 0);
            __builtin_amdgcn_global_load_lds(
                (const __attribute__((address_space(1))) unsigned int*)srcB,
                (__attribute__((address_space(3))) unsigned int*)((char*)&lds[buf][1][0] + c * 1024),
                16, 0, 0);
        }
    };

    stage(0, 0);
    __syncthreads();

    for (int kt = 0; kt < 16; ++kt) {
        int buf = kt & 1;
        if (kt + 1 < 16) stage(buf ^ 1, kt + 1);
        const char* Ab = (const char*)&lds[buf][0][0];
        const char* Bb = (const char*)&lds[buf][1][0];
#pragma unroll
        for (int ks = 0; ks < 2; ++ks) {
            short8 af[4], bg[4];
            int cb = ks * 64 + ((lane >> 4) << 4);
#pragma unroll
            for (int f = 0; f < 4; ++f) {
                int ar = wr * 64 + f * 16 + (lane & 15);
                int br = wc * 64 + f * 16 + (lane & 15);
                af[f] = *(const short8*)(Ab + ar * 128 + (cb ^ ((ar & 7) << 4)));
                bg[f] = *(const short8*)(Bb + br * 128 + (cb ^ ((br & 7) << 4)));
            }
#pragma unroll
            for (int fi = 0; fi < 4; ++fi)
#pragma unroll
                for (int fj = 0; fj < 4; ++fj)
                    acc[fi][fj] = __builtin_amdgcn_mfma_f32_16x16x32_bf16(
                        af[fi], bg[fj], acc[fi][fj], 0, 0, 0);
        }
        __syncthreads();
    }

    // epilogue: strict-causal mask, row-max over this wave's 64-col half,
    // write partial to part[b][sj*2+wc][t]
    int g = lane >> 4;
    int t0g = ti * 128 + wr * 64;
    int s0g = sj * 128 + wc * 64;
#pragma unroll
    for (int fi = 0; fi < 4; ++fi) {
#pragma unroll
        for (int r = 0; r < 4; ++r) {
            int trow = t0g + fi * 16 + g * 4 + r;
            float m = -2.0f;
#pragma unroll
            for (int fj = 0; fj < 4; ++fj) {
                int scol = s0g + fj * 16 + (lane & 15);
                m = fmaxf(m, (scol < trow) ? acc[fi][fj][r] : -2.0f);
            }
#pragma unroll
            for (int msk = 1; msk < 16; msk <<= 1) m = fmaxf(m, __shfl_xor(m, msk));
            if ((lane & 15) == 0)
                part[(((size_t)b * 32 + sj * 2 + wc) << 11) + trow] = m;
        }
    }
}

// ------- kernel C: reduce partials + gate + recompute gelu + scale -----------
__global__ void k_gate(const float* __restrict__ x, float* __restrict__ out,
                       const float* __restrict__ ema_sim,
                       const float* __restrict__ part,
                       const float* __restrict__ log_tau,
                       const float* __restrict__ log_blend,
                       const float* __restrict__ logit_blend_seq) {
    __shared__ float sgate;
    int row = blockIdx.x;
    int b = row >> 11;
    int t = row & (TT - 1);
    int tid = threadIdx.x;
    if (tid < 64) {
        int n = 2 * ((t >> 7) + 1);          // 2..32 column-halves present
        float m = (tid < n) ? part[(((size_t)b * 32 + tid) << 11) + t] : -2.0f;
#pragma unroll
        for (int msk = 1; msk < 32; msk <<= 1) m = fmaxf(m, __shfl_xor(m, msk));
        if (tid == 0) {
            float tau = expf(log_tau[0]);
            float alpha = 1.f / (1.f + expf(-log_blend[0]));
            float wseq = 1.f / (1.f + expf(-logit_blend_seq[0]));
            float es = ema_sim[row];
            float sq = (t > 0) ? m : es;
            float fam = wseq * sq + (1.f - wseq) * es;
            sgate = 1.f - alpha + alpha * expf(-tau * fam);
        }
    }
    __syncthreads();
    float gate = sgate;
    float4 v = reinterpret_cast<const float4*>(x + (size_t)row * DD)[tid];
    float4 o;
    o.x = fast_gelu(v.x) * gate;
    o.y = fast_gelu(v.y) * gate;
    o.z = fast_gelu(v.z) * gate;
    o.w = fast_gelu(v.w) * gate;
    reinterpret_cast<float4*>(out + (size_t)row * DD)[tid] = o;
}

extern "C" void kernel_launch(void* const* d_in, const int* in_sizes, int n_in,
                              void* d_out, int out_size, void* d_ws, size_t ws_size,
                              hipStream_t stream) {
    const float* x = (const float*)d_in[0];
    const float* ema = (const float*)d_in[1];
    // d_in[2] = logit_decay (unused by reference)
    const float* log_tau = (const float*)d_in[3];
    const float* log_blend = (const float*)d_in[4];
    const float* logit_bs = (const float*)d_in[5];
    float* out = (float*)d_out;

    char* ws = (char*)d_ws;
    float* ema_n = (float*)ws;                            // 4 KB
    float* ema_sim = (float*)(ws + (4 << 10));            // 64 KB
    float* part = (float*)(ws + (68 << 10));              // 2 MB (8*32*2048 f32)
    unsigned short* onrm = (unsigned short*)(ws + ((size_t)2176 << 10));  // 32 MB

    k_ema<<<1, 256, 0, stream>>>(ema, ema_n);
    k_gelu_norm<<<NB * TT, 256, 0, stream>>>(x, ema_n, onrm, ema_sim);
    k_seqmax<<<NB * NPAIR, 256, 0, stream>>>(onrm, part);
    k_gate<<<NB * TT, 256, 0, stream>>>(x, out, ema_sim, part, log_tau, log_blend, logit_bs);
}

// Round 4
// 93.683 us; speedup vs baseline: 10.3770x; 1.0817x over previous
//
#include <hip/hip_runtime.h>
#include <math.h>

#define NB 8
#define TT 2048
#define DD 1024
#define NTI 16            // 2048 / 128 t-tiles
#define NPAIR 136         // NTI*(NTI+1)/2

typedef __attribute__((ext_vector_type(8))) short short8;
typedef __attribute__((ext_vector_type(4))) float floatx4;

__device__ inline unsigned short f2bf(float f) {
    unsigned u = __builtin_bit_cast(unsigned, f);
    unsigned r = (u + 0x7fffu + ((u >> 16) & 1u)) >> 16;
    return (unsigned short)r;
}

__device__ inline float bf2f(unsigned short u) {
    return __builtin_bit_cast(float, (unsigned)u << 16);
}

__device__ inline float fast_gelu(float x) {
    // tanh(z) = 1 - 2/(exp(2z)+1); __expf -> v_exp_f32
    float z = 0.7978845608028654f * (x + 0.044715f * x * x * x);
    float e = __expf(2.0f * z);
    float th = 1.0f - 2.0f / (e + 1.0f);
    return 0.5f * x * (1.0f + th);
}

// ---------------- kernel 0: normalize ema (1 block, 256 threads) -------------
__global__ void k_ema(const float* __restrict__ ema, float* __restrict__ ema_n) {
    __shared__ float red[4];
    __shared__ float sinv;
    int tid = threadIdx.x;
    float4 v = reinterpret_cast<const float4*>(ema)[tid];
    float ss = v.x * v.x + v.y * v.y + v.z * v.z + v.w * v.w;
    for (int off = 32; off; off >>= 1) ss += __shfl_down(ss, off);
    if ((tid & 63) == 0) red[tid >> 6] = ss;
    __syncthreads();
    if (tid == 0) {
        float s = red[0] + red[1] + red[2] + red[3];
        sinv = 1.0f / fmaxf(sqrtf(s), 1e-12f);
    }
    __syncthreads();
    float inv = sinv;
    float4 o;
    o.x = v.x * inv; o.y = v.y * inv; o.z = v.z * inv; o.w = v.w * inv;
    reinterpret_cast<float4*>(ema_n)[tid] = o;
}

// ------- kernel A: gelu + row norm + ema dot, wave-per-row -------------------
// grid = NB*TT/4 blocks x 256 thr; wave w owns row blockIdx.x*4+w.
__global__ __launch_bounds__(256) void k_gelu_norm(
        const float* __restrict__ x, const float* __restrict__ ema_n,
        unsigned short* __restrict__ onrm, float* __restrict__ norms,
        float* __restrict__ ema_sim) {
    int row = blockIdx.x * 4 + (threadIdx.x >> 6);
    int lane = threadIdx.x & 63;
    const float4* xr = reinterpret_cast<const float4*>(x + (size_t)row * DD);
    const float4* er = reinterpret_cast<const float4*>(ema_n);
    float g[16];
    float ss = 0.f, dt = 0.f;
#pragma unroll
    for (int j = 0; j < 4; ++j) {
        float4 v = xr[j * 64 + lane];
        float4 e = er[j * 64 + lane];
        float vv[4] = {v.x, v.y, v.z, v.w};
        float ee[4] = {e.x, e.y, e.z, e.w};
#pragma unroll
        for (int i = 0; i < 4; ++i) {
            float o = fast_gelu(vv[i]);
            g[j * 4 + i] = o;
            ss += o * o;
            dt += o * ee[i];
        }
    }
#pragma unroll
    for (int m = 1; m < 64; m <<= 1) {
        ss += __shfl_xor(ss, m);
        dt += __shfl_xor(dt, m);
    }
    float nrm = fmaxf(sqrtf(ss), 1e-12f);
    float inv = 1.0f / nrm;
    ushort4* orow = reinterpret_cast<ushort4*>(onrm + (size_t)row * DD);
#pragma unroll
    for (int j = 0; j < 4; ++j) {
        ushort4 u;
        u.x = f2bf(g[j * 4 + 0] * inv);
        u.y = f2bf(g[j * 4 + 1] * inv);
        u.z = f2bf(g[j * 4 + 2] * inv);
        u.w = f2bf(g[j * 4 + 3] * inv);
        orow[j * 64 + lane] = u;
    }
    if (lane == 0) {
        norms[row] = nrm;
        ema_sim[row] = dt * inv;
    }
}

// -------- kernel B: causal max similarity, 128x128 tiled bf16 MFMA GEMM ------
// grid = NB*136 lower-tri 128x128 tile pairs, XCD-swizzled so each XCD owns
// one batch (4 MB onrm slice fits its 4 MB L2). 4 waves, each 64x64 (4x4
// frags), BK=64, double-buffered 64 KB LDS via global_load_lds w=16 with
// XOR-pre-swizzled global source (linear LDS dest).
__global__ void k_seqmax(const unsigned short* __restrict__ onrm,
                         float* __restrict__ part) {
    __shared__ unsigned short lds[2][2][8192];   // [buf][A/B][128 rows x 64 bf16]

    int id = blockIdx.x;
    int nid = (id & 7) * NPAIR + (id >> 3);      // bijective: 1088 % 8 == 0
    int b = nid / NPAIR;
    int p = nid % NPAIR;
    int ti = (int)((sqrtf(8.0f * (float)p + 1.0f) - 1.0f) * 0.5f);
    while ((ti + 1) * (ti + 2) / 2 <= p) ++ti;
    while (ti * (ti + 1) / 2 > p) --ti;
    int sj = p - ti * (ti + 1) / 2;

    int lane = threadIdx.x & 63;
    int wave = threadIdx.x >> 6;
    int wr = wave >> 1, wc = wave & 1;

    const unsigned short* Abase = onrm + (size_t)(b * TT + ti * 128) * DD;
    const unsigned short* Bbase = onrm + (size_t)(b * TT + sj * 128) * DD;

    floatx4 acc[4][4];
#pragma unroll
    for (int i = 0; i < 4; i++)
#pragma unroll
        for (int j = 0; j < 4; j++) acc[i][j] = (floatx4){0.f, 0.f, 0.f, 0.f};

    // stage 128x64 bf16 tiles (16 KB each): 16 chunks of 1 KB, 4 per wave.
    auto stage = [&](int buf, int kt) {
#pragma unroll
        for (int i = 0; i < 4; ++i) {
            int c = wave * 4 + i;            // chunk 0..15
            int off = c * 1024 + lane * 16;  // linear LDS byte offset
            int row = off >> 7;              // 128 B per row
            int colb = (off & 127) ^ ((row & 7) << 4);
            const char* srcA = (const char*)(Abase + (size_t)row * DD + kt * 64) + colb;
            const char* srcB = (const char*)(Bbase + (size_t)row * DD + kt * 64) + colb;
            __builtin_amdgcn_global_load_lds(
                (const __attribute__((address_space(1))) unsigned int*)srcA,
                (__attribute__((address_space(3))) unsigned int*)((char*)&lds[buf][0][0] + c * 1024),
                16, 0, 0);
            __builtin_amdgcn_global_load_lds(
                (const __attribute__((address_space(1))) unsigned int*)srcB,
                (__attribute__((address_space(3))) unsigned int*)((char*)&lds[buf][1][0] + c * 1024),
                16, 0, 0);
        }
    };

    stage(0, 0);
    __syncthreads();

    for (int kt = 0; kt < 16; ++kt) {
        int buf = kt & 1;
        if (kt + 1 < 16) stage(buf ^ 1, kt + 1);
        const char* Ab = (const char*)&lds[buf][0][0];
        const char* Bb = (const char*)&lds[buf][1][0];
#pragma unroll
        for (int ks = 0; ks < 2; ++ks) {
            short8 af[4], bg[4];
            int cb = ks * 64 + ((lane >> 4) << 4);
#pragma unroll
            for (int f = 0; f < 4; ++f) {
                int ar = wr * 64 + f * 16 + (lane & 15);
                int br = wc * 64 + f * 16 + (lane & 15);
                af[f] = *(const short8*)(Ab + ar * 128 + (cb ^ ((ar & 7) << 4)));
                bg[f] = *(const short8*)(Bb + br * 128 + (cb ^ ((br & 7) << 4)));
            }
#pragma unroll
            for (int fi = 0; fi < 4; ++fi)
#pragma unroll
                for (int fj = 0; fj < 4; ++fj)
                    acc[fi][fj] = __builtin_amdgcn_mfma_f32_16x16x32_bf16(
                        af[fi], bg[fj], acc[fi][fj], 0, 0, 0);
        }
        __syncthreads();
    }

    // epilogue: strict-causal mask, row-max over this wave's 64-col half,
    // write partial to part[b][sj*2+wc][t]
    int g = lane >> 4;
    int t0g = ti * 128 + wr * 64;
    int s0g = sj * 128 + wc * 64;
#pragma unroll
    for (int fi = 0; fi < 4; ++fi) {
#pragma unroll
        for (int r = 0; r < 4; ++r) {
            int trow = t0g + fi * 16 + g * 4 + r;
            float m = -2.0f;
#pragma unroll
            for (int fj = 0; fj < 4; ++fj) {
                int scol = s0g + fj * 16 + (lane & 15);
                m = fmaxf(m, (scol < trow) ? acc[fi][fj][r] : -2.0f);
            }
#pragma unroll
            for (int msk = 1; msk < 16; msk <<= 1) m = fmaxf(m, __shfl_xor(m, msk));
            if ((lane & 15) == 0)
                part[(((size_t)b * 32 + sj * 2 + wc) << 11) + trow] = m;
        }
    }
}

// ------- kernel C: reduce partials + gate + reconstruct out, wave-per-row ----
__global__ __launch_bounds__(256) void k_gate(
        const unsigned short* __restrict__ onrm, const float* __restrict__ norms,
        float* __restrict__ out, const float* __restrict__ ema_sim,
        const float* __restrict__ part,
        const float* __restrict__ log_tau,
        const float* __restrict__ log_blend,
        const float* __restrict__ logit_blend_seq) {
    int row = blockIdx.x * 4 + (threadIdx.x >> 6);
    int lane = threadIdx.x & 63;
    int b = row >> 11;
    int t = row & (TT - 1);

    int n = 2 * ((t >> 7) + 1);              // 2..32 column-halves present
    float m = (lane < n) ? part[(((size_t)b * 32 + lane) << 11) + t] : -2.0f;
#pragma unroll
    for (int msk = 1; msk < 64; msk <<= 1) m = fmaxf(m, __shfl_xor(m, msk));

    float tau = __expf(log_tau[0]);
    float alpha = 1.f / (1.f + __expf(-log_blend[0]));
    float wseq = 1.f / (1.f + __expf(-logit_blend_seq[0]));
    float es = ema_sim[row];
    float sq = (t > 0) ? m : es;
    float fam = wseq * sq + (1.f - wseq) * es;
    float gate = 1.f - alpha + alpha * __expf(-tau * fam);
    float scale = gate * norms[row];

    const ushort4* ir = reinterpret_cast<const ushort4*>(onrm + (size_t)row * DD);
    float4* orow = reinterpret_cast<float4*>(out + (size_t)row * DD);
#pragma unroll
    for (int j = 0; j < 4; ++j) {
        ushort4 u = ir[j * 64 + lane];
        float4 o;
        o.x = bf2f(u.x) * scale;
        o.y = bf2f(u.y) * scale;
        o.z = bf2f(u.z) * scale;
        o.w = bf2f(u.w) * scale;
        orow[j * 64 + lane] = o;
    }
}

extern "C" void kernel_launch(void* const* d_in, const int* in_sizes, int n_in,
                              void* d_out, int out_size, void* d_ws, size_t ws_size,
                              hipStream_t stream) {
    const float* x = (const float*)d_in[0];
    const float* ema = (const float*)d_in[1];
    // d_in[2] = logit_decay (unused by reference)
    const float* log_tau = (const float*)d_in[3];
    const float* log_blend = (const float*)d_in[4];
    const float* logit_bs = (const float*)d_in[5];
    float* out = (float*)d_out;

    char* ws = (char*)d_ws;
    float* ema_n = (float*)ws;                            // 4 KB
    float* ema_sim = (float*)(ws + (4 << 10));            // 64 KB
    float* norms = (float*)(ws + (68 << 10));             // 64 KB
    float* part = (float*)(ws + (132 << 10));             // 2 MB (8*32*2048 f32)
    unsigned short* onrm = (unsigned short*)(ws + ((size_t)2304 << 10));  // 32 MB

    k_ema<<<1, 256, 0, stream>>>(ema, ema_n);
    k_gelu_norm<<<NB * TT / 4, 256, 0, stream>>>(x, ema_n, onrm, norms, ema_sim);
    k_seqmax<<<NB * NPAIR, 256, 0, stream>>>(onrm, part);
    k_gate<<<NB * TT / 4, 256, 0, stream>>>(onrm, norms, out, ema_sim, part,
                                            log_tau, log_blend, logit_bs);
}

// Round 5
// 87.102 us; speedup vs baseline: 11.1611x; 1.0756x over previous
//
#include <hip/hip_runtime.h>
#include <math.h>

#define NB 8
#define TT 2048
#define DD 1024
#define NTI 16            // 2048 / 128 t-tiles
#define NPAIR 136         // NTI*(NTI+1)/2

typedef __attribute__((ext_vector_type(8))) short short8;
typedef __attribute__((ext_vector_type(4))) float floatx4;

__device__ inline unsigned short f2bf(float f) {
    unsigned u = __builtin_bit_cast(unsigned, f);
    unsigned r = (u + 0x7fffu + ((u >> 16) & 1u)) >> 16;
    return (unsigned short)r;
}

__device__ inline float bf2f(unsigned short u) {
    return __builtin_bit_cast(float, (unsigned)u << 16);
}

__device__ inline float fast_gelu(float x) {
    // tanh(z) = 1 - 2/(exp(2z)+1); __expf -> v_exp_f32
    float z = 0.7978845608028654f * (x + 0.044715f * x * x * x);
    float e = __expf(2.0f * z);
    float th = 1.0f - 2.0f / (e + 1.0f);
    return 0.5f * x * (1.0f + th);
}

// ------- kernel A: gelu + row norm + ema dot, wave-per-row -------------------
// grid = NB*TT/4 blocks x 256 thr; wave w owns row blockIdx.x*4+w.
// ema normalization fused: each wave computes ||ema|| itself (L2-hot 4KB).
__global__ __launch_bounds__(256) void k_gelu_norm(
        const float* __restrict__ x, const float* __restrict__ ema,
        unsigned short* __restrict__ onrm, float* __restrict__ norms,
        float* __restrict__ ema_sim) {
    int row = blockIdx.x * 4 + (threadIdx.x >> 6);
    int lane = threadIdx.x & 63;
    const float4* xr = reinterpret_cast<const float4*>(x + (size_t)row * DD);
    const float4* er = reinterpret_cast<const float4*>(ema);
    float g[16];
    float ss = 0.f, dt = 0.f, e2 = 0.f;
#pragma unroll
    for (int j = 0; j < 4; ++j) {
        float4 v = xr[j * 64 + lane];
        float4 e = er[j * 64 + lane];
        float vv[4] = {v.x, v.y, v.z, v.w};
        float ee[4] = {e.x, e.y, e.z, e.w};
        e2 += ee[0] * ee[0] + ee[1] * ee[1] + ee[2] * ee[2] + ee[3] * ee[3];
#pragma unroll
        for (int i = 0; i < 4; ++i) {
            float o = fast_gelu(vv[i]);
            g[j * 4 + i] = o;
            ss += o * o;
            dt += o * ee[i];
        }
    }
#pragma unroll
    for (int m = 1; m < 64; m <<= 1) {
        ss += __shfl_xor(ss, m);
        dt += __shfl_xor(dt, m);
        e2 += __shfl_xor(e2, m);
    }
    float nrm = fmaxf(sqrtf(ss), 1e-12f);
    float inv = 1.0f / nrm;
    float einv = 1.0f / fmaxf(sqrtf(e2), 1e-12f);
    ushort4* orow = reinterpret_cast<ushort4*>(onrm + (size_t)row * DD);
#pragma unroll
    for (int j = 0; j < 4; ++j) {
        ushort4 u;
        u.x = f2bf(g[j * 4 + 0] * inv);
        u.y = f2bf(g[j * 4 + 1] * inv);
        u.z = f2bf(g[j * 4 + 2] * inv);
        u.w = f2bf(g[j * 4 + 3] * inv);
        orow[j * 64 + lane] = u;
    }
    if (lane == 0) {
        norms[row] = nrm;
        ema_sim[row] = dt * inv * einv;
    }
}

// -------- kernel B: causal max similarity, 128x128 tiled bf16 MFMA GEMM ------
// grid = NB*136 lower-tri 128x128 tile pairs, XCD-swizzled so each XCD owns
// one batch (4 MB onrm slice fits its 4 MB L2). 4 waves, each 64x64 (4x4
// frags), BK=64. m97 single-buffer schedule: 32 KB LDS -> 4-5 blocks/CU;
// barrier drains hidden by cross-block wave overlap. global_load_lds w=16
// with XOR-pre-swizzled global source (linear LDS dest).
__global__ void k_seqmax(const unsigned short* __restrict__ onrm,
                         float* __restrict__ part) {
    __shared__ unsigned short lds[2][8192];   // [A/B][128 rows x 64 bf16] 32 KB

    int id = blockIdx.x;
    int nid = (id & 7) * NPAIR + (id >> 3);      // bijective: 1088 % 8 == 0
    int b = nid / NPAIR;
    int p = nid % NPAIR;
    int ti = (int)((sqrtf(8.0f * (float)p + 1.0f) - 1.0f) * 0.5f);
    while ((ti + 1) * (ti + 2) / 2 <= p) ++ti;
    while (ti * (ti + 1) / 2 > p) --ti;
    int sj = p - ti * (ti + 1) / 2;

    int lane = threadIdx.x & 63;
    int wave = threadIdx.x >> 6;
    int wr = wave >> 1, wc = wave & 1;

    const unsigned short* Abase = onrm + (size_t)(b * TT + ti * 128) * DD;
    const unsigned short* Bbase = onrm + (size_t)(b * TT + sj * 128) * DD;

    floatx4 acc[4][4];
#pragma unroll
    for (int i = 0; i < 4; i++)
#pragma unroll
        for (int j = 0; j < 4; j++) acc[i][j] = (floatx4){0.f, 0.f, 0.f, 0.f};

    // stage 128x64 bf16 tiles (16 KB each): 16 chunks of 1 KB, 4 per wave.
    auto stage = [&](int kt) {
#pragma unroll
        for (int i = 0; i < 4; ++i) {
            int c = wave * 4 + i;            // chunk 0..15
            int off = c * 1024 + lane * 16;  // linear LDS byte offset
            int row = off >> 7;              // 128 B per row
            int colb = (off & 127) ^ ((row & 7) << 4);
            const char* srcA = (const char*)(Abase + (size_t)row * DD + kt * 64) + colb;
            const char* srcB = (const char*)(Bbase + (size_t)row * DD + kt * 64) + colb;
            __builtin_amdgcn_global_load_lds(
                (const __attribute__((address_space(1))) unsigned int*)srcA,
                (__attribute__((address_space(3))) unsigned int*)((char*)&lds[0][0] + c * 1024),
                16, 0, 0);
            __builtin_amdgcn_global_load_lds(
                (const __attribute__((address_space(1))) unsigned int*)srcB,
                (__attribute__((address_space(3))) unsigned int*)((char*)&lds[1][0] + c * 1024),
                16, 0, 0);
        }
    };

    for (int kt = 0; kt < 16; ++kt) {
        stage(kt);
        __syncthreads();
        const char* Ab = (const char*)&lds[0][0];
        const char* Bb = (const char*)&lds[1][0];
#pragma unroll
        for (int ks = 0; ks < 2; ++ks) {
            short8 af[4], bg[4];
            int cb = ks * 64 + ((lane >> 4) << 4);
#pragma unroll
            for (int f = 0; f < 4; ++f) {
                int ar = wr * 64 + f * 16 + (lane & 15);
                int br = wc * 64 + f * 16 + (lane & 15);
                af[f] = *(const short8*)(Ab + ar * 128 + (cb ^ ((ar & 7) << 4)));
                bg[f] = *(const short8*)(Bb + br * 128 + (cb ^ ((br & 7) << 4)));
            }
#pragma unroll
            for (int fi = 0; fi < 4; ++fi)
#pragma unroll
                for (int fj = 0; fj < 4; ++fj)
                    acc[fi][fj] = __builtin_amdgcn_mfma_f32_16x16x32_bf16(
                        af[fi], bg[fj], acc[fi][fj], 0, 0, 0);
        }
        __syncthreads();
    }

    // epilogue: strict-causal mask, row-max over this wave's 64-col half,
    // write partial to part[b][sj*2+wc][t]
    int g = lane >> 4;
    int t0g = ti * 128 + wr * 64;
    int s0g = sj * 128 + wc * 64;
#pragma unroll
    for (int fi = 0; fi < 4; ++fi) {
#pragma unroll
        for (int r = 0; r < 4; ++r) {
            int trow = t0g + fi * 16 + g * 4 + r;
            float m = -2.0f;
#pragma unroll
            for (int fj = 0; fj < 4; ++fj) {
                int scol = s0g + fj * 16 + (lane & 15);
                m = fmaxf(m, (scol < trow) ? acc[fi][fj][r] : -2.0f);
            }
#pragma unroll
            for (int msk = 1; msk < 16; msk <<= 1) m = fmaxf(m, __shfl_xor(m, msk));
            if ((lane & 15) == 0)
                part[(((size_t)b * 32 + sj * 2 + wc) << 11) + trow] = m;
        }
    }
}

// ------- kernel C: reduce partials + gate + reconstruct out, wave-per-row ----
__global__ __launch_bounds__(256) void k_gate(
        const unsigned short* __restrict__ onrm, const float* __restrict__ norms,
        float* __restrict__ out, const float* __restrict__ ema_sim,
        const float* __restrict__ part,
        const float* __restrict__ log_tau,
        const float* __restrict__ log_blend,
        const float* __restrict__ logit_blend_seq) {
    int row = blockIdx.x * 4 + (threadIdx.x >> 6);
    int lane = threadIdx.x & 63;
    int b = row >> 11;
    int t = row & (TT - 1);

    int n = 2 * ((t >> 7) + 1);              // 2..32 column-halves present
    float m = (lane < n) ? part[(((size_t)b * 32 + lane) << 11) + t] : -2.0f;
#pragma unroll
    for (int msk = 1; msk < 64; msk <<= 1) m = fmaxf(m, __shfl_xor(m, msk));

    float tau = __expf(log_tau[0]);
    float alpha = 1.f / (1.f + __expf(-log_blend[0]));
    float wseq = 1.f / (1.f + __expf(-logit_blend_seq[0]));
    float es = ema_sim[row];
    float sq = (t > 0) ? m : es;
    float fam = wseq * sq + (1.f - wseq) * es;
    float gate = 1.f - alpha + alpha * __expf(-tau * fam);
    float scale = gate * norms[row];

    const ushort4* ir = reinterpret_cast<const ushort4*>(onrm + (size_t)row * DD);
    float4* orow = reinterpret_cast<float4*>(out + (size_t)row * DD);
#pragma unroll
    for (int j = 0; j < 4; ++j) {
        ushort4 u = ir[j * 64 + lane];
        float4 o;
        o.x = bf2f(u.x) * scale;
        o.y = bf2f(u.y) * scale;
        o.z = bf2f(u.z) * scale;
        o.w = bf2f(u.w) * scale;
        orow[j * 64 + lane] = o;
    }
}

extern "C" void kernel_launch(void* const* d_in, const int* in_sizes, int n_in,
                              void* d_out, int out_size, void* d_ws, size_t ws_size,
                              hipStream_t stream) {
    const float* x = (const float*)d_in[0];
    const float* ema = (const float*)d_in[1];
    // d_in[2] = logit_decay (unused by reference)
    const float* log_tau = (const float*)d_in[3];
    const float* log_blend = (const float*)d_in[4];
    const float* logit_bs = (const float*)d_in[5];
    float* out = (float*)d_out;

    char* ws = (char*)d_ws;
    float* ema_sim = (float*)(ws + (4 << 10));            // 64 KB
    float* norms = (float*)(ws + (68 << 10));             // 64 KB
    float* part = (float*)(ws + (132 << 10));             // 2 MB (8*32*2048 f32)
    unsigned short* onrm = (unsigned short*)(ws + ((size_t)2304 << 10));  // 32 MB

    k_gelu_norm<<<NB * TT / 4, 256, 0, stream>>>(x, ema, onrm, norms, ema_sim);
    k_seqmax<<<NB * NPAIR, 256, 0, stream>>>(onrm, part);
    k_gate<<<NB * TT / 4, 256, 0, stream>>>(onrm, norms, out, ema_sim, part,
                                            log_tau, log_blend, logit_bs);
}